// Round 3
// baseline (234.213 us; speedup 1.0000x reference)
//
#include <hip/hip_runtime.h>
#include <hip/hip_cooperative_groups.h>

namespace cg = cooperative_groups;

// change[i] (i>=1) ∝ (g(i-3) - g(i+2))^2   with g(k)=f[k] zero-padded; change[0]=0
// out[i] = (1 - change[i]/S)^5 * f[i],  S = sum(change)
// The 1/5 conv scaling cancels in change[i]/S, so we accumulate unscaled d^2.
//
// R8: SINGLE cooperative dispatch (grid-wide sync between reduce and finalize).
//  - resolves the "is inter-dispatch overhead the remaining cost?" question:
//    R0 (3 dispatches) = 119us, R7 (2 dispatches) = 124us was ambiguous noise.
//  - phase 1: grid-stride d^2 reduce -> partials[bid] (plain store, no init).
//  - grid.sync(); every block folds partials (<=8 loads/thread, L2-resident).
//  - phase 2: grid-stride finalize, f re-read is L3-warm, NT stores for out.
//  - grid clamped to guaranteed co-residency via occupancy query (cached).
//  - fallback: 2-kernel non-cooperative path if hipLaunchCooperativeKernel
//    is rejected (e.g. under graph capture on an unsupported stack).

#define BLOCK 256
#define CGRID_MAX 2048

typedef __attribute__((ext_vector_type(4))) float vfloat4;

__device__ __forceinline__ float change_term(const float* __restrict__ f, long long i, long long n) {
    if (i < 1) return 0.0f;
    float a = (i >= 3)    ? f[i - 3] : 0.0f;
    float b = (i + 2 < n) ? f[i + 2] : 0.0f;
    float d = a - b;
    return d * d;
}

__device__ __forceinline__ float pow5(float t) {
    float t2 = t * t;
    float t4 = t2 * t2;
    return t4 * t;
}

// terms for vector v given p=fv[v-1], c=fv[v], q=fv[v+1]; element j=4v+k uses
// a=f[j-3], b=f[j+2]
__device__ __forceinline__ float vec_terms(float4 p, float4 c, float4 q) {
    float d0 = p.y - c.z;
    float d1 = p.z - c.w;
    float d2 = p.w - q.x;
    float d3 = c.x - q.y;
    return d0 * d0 + d1 * d1 + d2 * d2 + d3 * d3;
}

__device__ __forceinline__ vfloat4 vec_out(float4 p, float4 c, float4 q, float inv) {
    float d0 = p.y - c.z;
    float d1 = p.z - c.w;
    float d2 = p.w - q.x;
    float d3 = c.x - q.y;
    vfloat4 o;
    o.x = pow5(1.0f - d0 * d0 * inv) * c.x;
    o.y = pow5(1.0f - d1 * d1 * inv) * c.y;
    o.z = pow5(1.0f - d2 * d2 * inv) * c.z;
    o.w = pow5(1.0f - d3 * d3 * inv) * c.w;
    return o;
}

// ---------------- single-dispatch cooperative kernel ----------------

__global__ __launch_bounds__(BLOCK, 4)
void fused_kernel(const float* __restrict__ f, int nvec, long long n,
                  float* __restrict__ partials, float* __restrict__ out) {
    const float4* __restrict__ fv = (const float4*)f;
    vfloat4* __restrict__ ov = (vfloat4*)out;
    const int T = gridDim.x * BLOCK;
    const int tid = blockIdx.x * BLOCK + threadIdx.x;
    const int M = nvec - 2;  // interior vectors: v = 1 + idx, idx in [0, M)

    // ---- phase 1: d^2 reduction (12 coalesced float4 loads in flight) ----
    float acc = 0.0f;
    int idx = tid;
    for (; idx + 3 * T < M; idx += 4 * T) {
        float4 p[4], c[4], q[4];
        #pragma unroll
        for (int u = 0; u < 4; ++u) {
            int v = 1 + idx + u * T;
            p[u] = fv[v - 1];
            c[u] = fv[v];
            q[u] = fv[v + 1];
        }
        #pragma unroll
        for (int u = 0; u < 4; ++u)
            acc += vec_terms(p[u], c[u], q[u]);
    }
    for (; idx < M; idx += T) {
        int v = 1 + idx;
        acc += vec_terms(fv[v - 1], fv[v], fv[v + 1]);
    }
    if (tid == 0) {
        #pragma unroll
        for (int k = 0; k < 4; ++k) acc += change_term(f, k, n);
        long long j0 = n - 4;
        #pragma unroll
        for (int k = 0; k < 4; ++k) acc += change_term(f, j0 + k, n);
    }

    #pragma unroll
    for (int off = 32; off > 0; off >>= 1)
        acc += __shfl_down(acc, off, 64);
    __shared__ float smem[4];
    __shared__ float stot;
    int lane = threadIdx.x & 63;
    int wave = threadIdx.x >> 6;
    if (lane == 0) smem[wave] = acc;
    __syncthreads();
    if (threadIdx.x == 0)
        partials[blockIdx.x] = smem[0] + smem[1] + smem[2] + smem[3];

    // ---- grid-wide barrier: partials complete & visible ----
    cg::this_grid().sync();

    // ---- every block folds the partials (L2-resident, <=8 loads/thread) ----
    float s = 0.0f;
    for (int k = threadIdx.x; k < (int)gridDim.x; k += BLOCK)
        s += partials[k];
    #pragma unroll
    for (int off = 32; off > 0; off >>= 1)
        s += __shfl_down(s, off, 64);
    if (lane == 0) smem[wave] = s;
    __syncthreads();
    if (threadIdx.x == 0) stot = smem[0] + smem[1] + smem[2] + smem[3];
    __syncthreads();
    const float inv = 1.0f / stot;

    // ---- phase 2: finalize, f is L3-warm, NT stores (write-once) ----
    idx = tid;
    for (; idx + 3 * T < M; idx += 4 * T) {
        float4 p[4], c[4], q[4];
        #pragma unroll
        for (int u = 0; u < 4; ++u) {
            int v = 1 + idx + u * T;
            p[u] = fv[v - 1];
            c[u] = fv[v];
            q[u] = fv[v + 1];
        }
        #pragma unroll
        for (int u = 0; u < 4; ++u)
            __builtin_nontemporal_store(vec_out(p[u], c[u], q[u], inv), &ov[1 + idx + u * T]);
    }
    for (; idx < M; idx += T) {
        int v = 1 + idx;
        __builtin_nontemporal_store(vec_out(fv[v - 1], fv[v], fv[v + 1], inv), &ov[v]);
    }
    if (tid == 0) {
        #pragma unroll
        for (int k = 0; k < 4; ++k) {
            float cge = change_term(f, k, n) * inv;
            out[k] = pow5(1.0f - cge) * f[k];
        }
        long long j0 = n - 4;
        #pragma unroll
        for (int k = 0; k < 4; ++k) {
            long long j = j0 + k;
            float cge = change_term(f, j, n) * inv;
            out[j] = pow5(1.0f - cge) * f[j];
        }
    }
}

// ---------------- fallback: non-cooperative 2-dispatch path ----------------

__global__ __launch_bounds__(BLOCK)
void reduce_change_kernel(const float* __restrict__ f, int nvec, long long n,
                          float* __restrict__ partials) {
    const float4* __restrict__ fv = (const float4*)f;
    const int T = gridDim.x * BLOCK;
    const int tid = blockIdx.x * BLOCK + threadIdx.x;
    const int M = nvec - 2;
    float acc = 0.0f;
    int idx = tid;
    for (; idx + 3 * T < M; idx += 4 * T) {
        float4 p[4], c[4], q[4];
        #pragma unroll
        for (int u = 0; u < 4; ++u) {
            int v = 1 + idx + u * T;
            p[u] = fv[v - 1];
            c[u] = fv[v];
            q[u] = fv[v + 1];
        }
        #pragma unroll
        for (int u = 0; u < 4; ++u)
            acc += vec_terms(p[u], c[u], q[u]);
    }
    for (; idx < M; idx += T) {
        int v = 1 + idx;
        acc += vec_terms(fv[v - 1], fv[v], fv[v + 1]);
    }
    if (tid == 0) {
        #pragma unroll
        for (int k = 0; k < 4; ++k) acc += change_term(f, k, n);
        long long j0 = n - 4;
        #pragma unroll
        for (int k = 0; k < 4; ++k) acc += change_term(f, j0 + k, n);
    }
    #pragma unroll
    for (int off = 32; off > 0; off >>= 1)
        acc += __shfl_down(acc, off, 64);
    __shared__ float smem[4];
    int lane = threadIdx.x & 63;
    int wave = threadIdx.x >> 6;
    if (lane == 0) smem[wave] = acc;
    __syncthreads();
    if (threadIdx.x == 0)
        partials[blockIdx.x] = smem[0] + smem[1] + smem[2] + smem[3];
}

__global__ __launch_bounds__(BLOCK)
void finalize_kernel(const float* __restrict__ f, int nvec, long long n,
                     const float* __restrict__ partials, int npart,
                     float* __restrict__ out) {
    const float4* __restrict__ fv = (const float4*)f;
    vfloat4* __restrict__ ov = (vfloat4*)out;
    const int M = nvec - 2;
    const int T = (M + 3) >> 2;
    const int tid = blockIdx.x * BLOCK + threadIdx.x;

    bool active = tid < T;
    int i0 = active ? tid : 0;
    bool ok1 = active && (i0 + 1 * T < M);
    bool ok2 = active && (i0 + 2 * T < M);
    bool ok3 = active && (i0 + 3 * T < M);
    int v0 = 1 + i0;
    int v1 = ok1 ? v0 + T : v0;
    int v2 = ok2 ? v1 + T : v1;
    int v3 = ok3 ? v2 + T : v2;
    float4 p0 = fv[v0 - 1], c0 = fv[v0], q0 = fv[v0 + 1];
    float4 p1 = fv[v1 - 1], c1 = fv[v1], q1 = fv[v1 + 1];
    float4 p2 = fv[v2 - 1], c2 = fv[v2], q2 = fv[v2 + 1];
    float4 p3 = fv[v3 - 1], c3 = fv[v3], q3 = fv[v3 + 1];

    float s = 0.0f;
    for (int k = threadIdx.x; k < npart; k += BLOCK)
        s += partials[k];
    #pragma unroll
    for (int off = 32; off > 0; off >>= 1)
        s += __shfl_down(s, off, 64);
    __shared__ float smem[4];
    __shared__ float stot;
    int lane = threadIdx.x & 63;
    int wave = threadIdx.x >> 6;
    if (lane == 0) smem[wave] = s;
    __syncthreads();
    if (threadIdx.x == 0) stot = smem[0] + smem[1] + smem[2] + smem[3];
    __syncthreads();
    float inv = 1.0f / stot;

    if (active) {
        __builtin_nontemporal_store(vec_out(p0, c0, q0, inv), &ov[v0]);
        if (ok1) __builtin_nontemporal_store(vec_out(p1, c1, q1, inv), &ov[v1]);
        if (ok2) __builtin_nontemporal_store(vec_out(p2, c2, q2, inv), &ov[v2]);
        if (ok3) __builtin_nontemporal_store(vec_out(p3, c3, q3, inv), &ov[v3]);
    }
    if (tid == 0) {
        #pragma unroll
        for (int k = 0; k < 4; ++k) {
            float cge = change_term(f, k, n) * inv;
            out[k] = pow5(1.0f - cge) * f[k];
        }
        long long j0 = n - 4;
        #pragma unroll
        for (int k = 0; k < 4; ++k) {
            long long j = j0 + k;
            float cge = change_term(f, j, n) * inv;
            out[j] = pow5(1.0f - cge) * f[j];
        }
    }
}

// ---------------- host ----------------

extern "C" void kernel_launch(void* const* d_in, const int* in_sizes, int n_in,
                              void* d_out, int out_size, void* d_ws, size_t ws_size,
                              hipStream_t stream) {
    const float* f = (const float*)d_in[0];
    float* out = (float*)d_out;
    float* partials = (float*)d_ws;
    long long n = (long long)in_sizes[0];
    int nvec = (int)(n / 4);  // n = 2^24, divisible by 4

    // one-time occupancy query (host-side only; safe under graph capture)
    static int coop_grid = -1;
    static bool coop_ok = true;
    if (coop_grid < 0) {
        int dev = 0;
        (void)hipGetDevice(&dev);
        int ncu = 0;
        if (hipDeviceGetAttribute(&ncu, hipDeviceAttributeMultiprocessorCount, dev) != hipSuccess || ncu <= 0)
            ncu = 256;
        int blocks_per_cu = 0;
        if (hipOccupancyMaxActiveBlocksPerMultiprocessor(&blocks_per_cu, fused_kernel, BLOCK, 0) != hipSuccess
            || blocks_per_cu <= 0) {
            coop_ok = false;
            blocks_per_cu = 1;
        }
        long long g = (long long)blocks_per_cu * ncu;
        if (g > CGRID_MAX) g = CGRID_MAX;
        if (ws_size > 0 && (size_t)g * sizeof(float) > ws_size)
            g = (long long)(ws_size / sizeof(float));
        if (g < 1) { g = 1; coop_ok = false; }
        coop_grid = (int)g;
    }

    if (coop_ok) {
        void* args[] = {(void*)&f, (void*)&nvec, (void*)&n, (void*)&partials, (void*)&out};
        hipError_t err = hipLaunchCooperativeKernel((const void*)fused_kernel,
                                                    dim3((unsigned)coop_grid), dim3(BLOCK),
                                                    args, 0, stream);
        if (err == hipSuccess) return;
        coop_ok = false;  // fall through to 2-dispatch path (and skip retries)
    }

    int rgrid = coop_grid > 0 ? coop_grid : 1024;
    reduce_change_kernel<<<rgrid, BLOCK, 0, stream>>>(f, nvec, n, partials);
    int M = nvec - 2;
    int T = (M + 3) >> 2;
    int fgrid = (T + BLOCK - 1) / BLOCK;
    finalize_kernel<<<fgrid, BLOCK, 0, stream>>>(f, nvec, n, partials, rgrid, out);
}

// Round 4
// 188.234 us; speedup vs baseline: 1.2443x; 1.2443x over previous
//
#include <hip/hip_runtime.h>

// change[i] (i>=1) ∝ (g(i-3) - g(i+2))^2   with g(k)=f[k] zero-padded; change[0]=0
// out[i] = (1 - change[i]/S)^5 * f[i],  S = sum(change)
// The 1/5 conv scaling cancels in change[i]/S, so we accumulate unscaled d^2.
//
// R9: back to 2 dispatches (R8's cooperative grid.sync cost ~170us at 2048
// blocks: 588 GB/s, VALUBusy 2.3% -- barrier spin dominated). Speed up the
// kernels themselves instead:
//  - 64B-group processing: each thread handles 4 ADJACENT float4 vectors via
//    6 loads (p, c0..c3, q) = 1.5 VMEM per 16B instead of 3 (p/c/q per vector).
//    All 16 terms computed from a 24-float register window, static indices.
//  - edges (first/last 16 elements) by 32 lanes of block 0, scalar change_term.
//  - reduce: plain store of block partial (no init, no atomics, no memset).
//  - finalize: issue 6 f-loads first, fold partials under their latency,
//    4 nontemporal 16B stores per thread.

#define BLOCK 256
#define RGRID_MAX 2048

typedef __attribute__((ext_vector_type(4))) float vfloat4;

__device__ __forceinline__ float change_term(const float* __restrict__ f, long long i, long long n) {
    if (i < 1) return 0.0f;
    float a = (i >= 3)    ? f[i - 3] : 0.0f;
    float b = (i + 2 < n) ? f[i + 2] : 0.0f;
    float d = a - b;
    return d * d;
}

__device__ __forceinline__ float pow5(float t) {
    float t2 = t * t;
    float t4 = t2 * t2;
    return t4 * t;
}

// Unpack 6 float4 (window f[16i-4 .. 16i+20)) into L[24].
__device__ __forceinline__ void unpack24(const float4* A, float* L) {
    #pragma unroll
    for (int u = 0; u < 6; ++u) {
        L[4 * u + 0] = A[u].x;
        L[4 * u + 1] = A[u].y;
        L[4 * u + 2] = A[u].z;
        L[4 * u + 3] = A[u].w;
    }
}

// sum of 16 terms for group i: element j=16i+k uses a=f[j-3]=L[k+1], b=f[j+2]=L[k+6]
__device__ __forceinline__ float group_terms(const float4* A) {
    float L[24];
    unpack24(A, L);
    float s = 0.0f;
    #pragma unroll
    for (int k = 0; k < 16; ++k) {
        float d = L[k + 1] - L[k + 6];
        s = fmaf(d, d, s);
    }
    return s;
}

__global__ __launch_bounds__(BLOCK)
void reduce_change_kernel(const float* __restrict__ f, int nvec, long long n,
                          float* __restrict__ partials) {
    const float4* __restrict__ fv = (const float4*)f;
    const int G = nvec >> 2;   // 64B groups
    const int NG = G - 2;      // interior groups: i = 1 + g, g in [0, NG)
    const int T = gridDim.x * BLOCK;
    const int tid = blockIdx.x * BLOCK + threadIdx.x;
    float acc = 0.0f;

    int g = tid;
    // two independent groups in flight: 12 float4 loads outstanding
    for (; g + T < NG; g += 2 * T) {
        int i0 = 1 + g;
        int i1 = 1 + g + T;
        float4 A[6], B[6];
        A[0] = fv[4 * i0 - 1];
        B[0] = fv[4 * i1 - 1];
        #pragma unroll
        for (int u = 0; u < 4; ++u) {
            A[1 + u] = fv[4 * i0 + u];
            B[1 + u] = fv[4 * i1 + u];
        }
        A[5] = fv[4 * i0 + 4];
        B[5] = fv[4 * i1 + 4];
        acc += group_terms(A);
        acc += group_terms(B);
    }
    for (; g < NG; g += T) {
        int i0 = 1 + g;
        float4 A[6];
        A[0] = fv[4 * i0 - 1];
        #pragma unroll
        for (int u = 0; u < 4; ++u) A[1 + u] = fv[4 * i0 + u];
        A[5] = fv[4 * i0 + 4];
        acc += group_terms(A);
    }

    // edge elements j in [0,16) U [n-16, n): 32 lanes of block 0
    if (blockIdx.x == 0 && threadIdx.x < 32) {
        long long j = (threadIdx.x < 16) ? (long long)threadIdx.x
                                         : (n - 16 + (threadIdx.x - 16));
        acc += change_term(f, j, n);
    }

    // wave (64-lane) reduction, then 4-wave LDS fold
    #pragma unroll
    for (int off = 32; off > 0; off >>= 1)
        acc += __shfl_down(acc, off, 64);
    __shared__ float smem[4];
    int lane = threadIdx.x & 63;
    int wave = threadIdx.x >> 6;
    if (lane == 0) smem[wave] = acc;
    __syncthreads();
    if (threadIdx.x == 0)
        partials[blockIdx.x] = smem[0] + smem[1] + smem[2] + smem[3];  // plain store
}

__global__ __launch_bounds__(BLOCK)
void finalize_kernel(const float* __restrict__ f, int nvec, long long n,
                     const float* __restrict__ partials, int npart,
                     float* __restrict__ out) {
    const float4* __restrict__ fv = (const float4*)f;
    vfloat4* __restrict__ ov = (vfloat4*)out;
    const int G = nvec >> 2;
    const int NG = G - 2;      // one interior group per thread
    const int tid = blockIdx.x * BLOCK + threadIdx.x;

    // ---- issue the 6 f-loads first; partial-fold hides their latency ----
    bool active = tid < NG;
    int i = 1 + (active ? tid : 0);
    float4 A[6];
    A[0] = fv[4 * i - 1];
    #pragma unroll
    for (int u = 0; u < 4; ++u) A[1 + u] = fv[4 * i + u];
    A[5] = fv[4 * i + 4];

    // ---- fold the npart partial sums (L2-resident, coalesced) ----
    float s = 0.0f;
    for (int k = threadIdx.x; k < npart; k += BLOCK)
        s += partials[k];
    #pragma unroll
    for (int off = 32; off > 0; off >>= 1)
        s += __shfl_down(s, off, 64);
    __shared__ float smem[4];
    __shared__ float stot;
    int lane = threadIdx.x & 63;
    int wave = threadIdx.x >> 6;
    if (lane == 0) smem[wave] = s;
    __syncthreads();
    if (threadIdx.x == 0) stot = smem[0] + smem[1] + smem[2] + smem[3];
    __syncthreads();
    const float inv = 1.0f / stot;

    // ---- compute 16 outputs, 4 nontemporal 16B stores ----
    if (active) {
        float L[24];
        unpack24(A, L);
        float o[16];
        #pragma unroll
        for (int k = 0; k < 16; ++k) {
            float d = L[k + 1] - L[k + 6];
            o[k] = pow5(1.0f - d * d * inv) * L[k + 4];   // c = f[16i+k] = L[k+4]
        }
        #pragma unroll
        for (int u = 0; u < 4; ++u) {
            vfloat4 v;
            v.x = o[4 * u + 0];
            v.y = o[4 * u + 1];
            v.z = o[4 * u + 2];
            v.w = o[4 * u + 3];
            __builtin_nontemporal_store(v, &ov[4 * i + u]);
        }
    }

    // edge elements j in [0,16) U [n-16, n)
    if (blockIdx.x == 0 && threadIdx.x < 32) {
        long long j = (threadIdx.x < 16) ? (long long)threadIdx.x
                                         : (n - 16 + (threadIdx.x - 16));
        float cge = change_term(f, j, n) * inv;
        out[j] = pow5(1.0f - cge) * f[j];
    }
}

extern "C" void kernel_launch(void* const* d_in, const int* in_sizes, int n_in,
                              void* d_out, int out_size, void* d_ws, size_t ws_size,
                              hipStream_t stream) {
    const float* f = (const float*)d_in[0];
    float* out = (float*)d_out;
    float* partials = (float*)d_ws;
    long long n = (long long)in_sizes[0];
    int nvec = (int)(n / 4);  // n = 2^24, divisible by 4

    // clamp reduce grid so partials[] (rgrid floats) always fits in ws_size
    int rgrid = RGRID_MAX;
    if (ws_size > 0 && (size_t)rgrid * sizeof(float) > ws_size) {
        rgrid = (int)(ws_size / sizeof(float));
        if (rgrid > RGRID_MAX) rgrid = RGRID_MAX;
        if (rgrid < 1) rgrid = 1;
    }

    reduce_change_kernel<<<rgrid, BLOCK, 0, stream>>>(f, nvec, n, partials);

    int G = nvec >> 2;
    int NG = G - 2;
    int fgrid = (NG + BLOCK - 1) / BLOCK;
    finalize_kernel<<<fgrid, BLOCK, 0, stream>>>(f, nvec, n, partials, rgrid, out);
}

// Round 5
// 122.904 us; speedup vs baseline: 1.9057x; 1.5316x over previous
//
#include <hip/hip_runtime.h>

// change[i] (i>=1) ∝ (g(i-3) - g(i+2))^2   with g(k)=f[k] zero-padded; change[0]=0
// out[i] = (1 - change[i]/S)^5 * f[i],  S = sum(change)
// The 1/5 conv scaling cancels in change[i]/S, so we accumulate unscaled d^2.
//
// R10: revert R9's 64B-group layout. Its per-instruction 64B lane stride broke
// coalescing: WRITE_SIZE 189MB vs 64MB ideal (NT partial-line RMW, 3x write
// amplification, finalize 101us @ 2.2TB/s) and 4x L2 sector traffic on loads.
// Coalescing is a PER-INSTRUCTION property: lane-contiguous 16B beats
// fewer-but-strided accesses.
// Structure = R7 (best-known): 2 dispatches, strided per-vector layout,
// every load/store instruction lane-contiguous (1KB/instr), plain partial
// stores (no memset/atomics), finalize folds partials under pre-issued loads,
// NT full-line stores for write-once out.

#define BLOCK 256
#define RGRID_MAX 2048

typedef __attribute__((ext_vector_type(4))) float vfloat4;

__device__ __forceinline__ float change_term(const float* __restrict__ f, long long i, long long n) {
    if (i < 1) return 0.0f;
    float a = (i >= 3)    ? f[i - 3] : 0.0f;
    float b = (i + 2 < n) ? f[i + 2] : 0.0f;
    float d = a - b;
    return d * d;
}

__device__ __forceinline__ float pow5(float t) {
    float t2 = t * t;
    float t4 = t2 * t2;
    return t4 * t;
}

// terms for vector v given p=fv[v-1], c=fv[v], q=fv[v+1]; element j=4v+k uses
// a=f[j-3], b=f[j+2]
__device__ __forceinline__ float vec_terms(float4 p, float4 c, float4 q) {
    float d0 = p.y - c.z;
    float d1 = p.z - c.w;
    float d2 = p.w - q.x;
    float d3 = c.x - q.y;
    return d0 * d0 + d1 * d1 + d2 * d2 + d3 * d3;
}

__device__ __forceinline__ vfloat4 vec_out(float4 p, float4 c, float4 q, float inv) {
    float d0 = p.y - c.z;
    float d1 = p.z - c.w;
    float d2 = p.w - q.x;
    float d3 = c.x - q.y;
    vfloat4 o;
    o.x = pow5(1.0f - d0 * d0 * inv) * c.x;
    o.y = pow5(1.0f - d1 * d1 * inv) * c.y;
    o.z = pow5(1.0f - d2 * d2 * inv) * c.z;
    o.w = pow5(1.0f - d3 * d3 * inv) * c.w;
    return o;
}

__global__ __launch_bounds__(BLOCK)
void reduce_change_kernel(const float* __restrict__ f, int nvec, long long n,
                          float* __restrict__ partials) {
    const float4* __restrict__ fv = (const float4*)f;
    const int T = gridDim.x * BLOCK;
    const int tid = blockIdx.x * BLOCK + threadIdx.x;
    const int M = nvec - 2;  // interior vectors: v = 1 + idx, idx in [0, M)
    float acc = 0.0f;

    int idx = tid;
    // unrolled-by-4: 12 independent, perfectly-coalesced float4 loads in flight
    for (; idx + 3 * T < M; idx += 4 * T) {
        float4 p[4], c[4], q[4];
        #pragma unroll
        for (int u = 0; u < 4; ++u) {
            int v = 1 + idx + u * T;
            p[u] = fv[v - 1];
            c[u] = fv[v];
            q[u] = fv[v + 1];
        }
        #pragma unroll
        for (int u = 0; u < 4; ++u)
            acc += vec_terms(p[u], c[u], q[u]);
    }
    for (; idx < M; idx += T) {
        int v = 1 + idx;
        acc += vec_terms(fv[v - 1], fv[v], fv[v + 1]);
    }
    if (tid == 0) {
        #pragma unroll
        for (int k = 0; k < 4; ++k) acc += change_term(f, k, n);
        long long j0 = n - 4;
        #pragma unroll
        for (int k = 0; k < 4; ++k) acc += change_term(f, j0 + k, n);
    }

    // wave (64-lane) reduction
    #pragma unroll
    for (int off = 32; off > 0; off >>= 1)
        acc += __shfl_down(acc, off, 64);
    __shared__ float smem[4];
    int lane = threadIdx.x & 63;
    int wave = threadIdx.x >> 6;
    if (lane == 0) smem[wave] = acc;
    __syncthreads();
    if (threadIdx.x == 0)
        partials[blockIdx.x] = smem[0] + smem[1] + smem[2] + smem[3];  // plain store, no init needed
}

__global__ __launch_bounds__(BLOCK)
void finalize_kernel(const float* __restrict__ f, int nvec, long long n,
                     const float* __restrict__ partials, int npart,
                     float* __restrict__ out) {
    const float4* __restrict__ fv = (const float4*)f;
    vfloat4* __restrict__ ov = (vfloat4*)out;
    const int M = nvec - 2;       // interior vectors
    const int T = (M + 3) >> 2;   // 4 strided interior vectors per thread
    const int tid = blockIdx.x * BLOCK + threadIdx.x;

    // ---- issue all 12 f loads first (latency hides under the partial fold) ----
    bool active = tid < T;
    int i0 = active ? tid : 0;
    bool ok1 = active && (i0 + 1 * T < M);
    bool ok2 = active && (i0 + 2 * T < M);
    bool ok3 = active && (i0 + 3 * T < M);
    int v0 = 1 + i0;
    int v1 = ok1 ? v0 + T : v0;
    int v2 = ok2 ? v1 + T : v1;
    int v3 = ok3 ? v2 + T : v2;
    float4 p0 = fv[v0 - 1], c0 = fv[v0], q0 = fv[v0 + 1];
    float4 p1 = fv[v1 - 1], c1 = fv[v1], q1 = fv[v1 + 1];
    float4 p2 = fv[v2 - 1], c2 = fv[v2], q2 = fv[v2 + 1];
    float4 p3 = fv[v3 - 1], c3 = fv[v3], q3 = fv[v3 + 1];

    // ---- fold the npart partial sums (coalesced, L2-resident) ----
    float s = 0.0f;
    for (int k = threadIdx.x; k < npart; k += BLOCK)
        s += partials[k];
    #pragma unroll
    for (int off = 32; off > 0; off >>= 1)
        s += __shfl_down(s, off, 64);
    __shared__ float smem[4];
    __shared__ float stot;
    int lane = threadIdx.x & 63;
    int wave = threadIdx.x >> 6;
    if (lane == 0) smem[wave] = s;
    __syncthreads();
    if (threadIdx.x == 0) stot = smem[0] + smem[1] + smem[2] + smem[3];
    __syncthreads();
    float inv = 1.0f / stot;

    // ---- compute + nontemporal stores (full-line coalesced: lane-contiguous 16B) ----
    if (active) {
        __builtin_nontemporal_store(vec_out(p0, c0, q0, inv), &ov[v0]);
        if (ok1) __builtin_nontemporal_store(vec_out(p1, c1, q1, inv), &ov[v1]);
        if (ok2) __builtin_nontemporal_store(vec_out(p2, c2, q2, inv), &ov[v2]);
        if (ok3) __builtin_nontemporal_store(vec_out(p3, c3, q3, inv), &ov[v3]);
    }
    if (tid == 0) {
        // edge vectors v=0 and v=nvec-1, scalar
        #pragma unroll
        for (int k = 0; k < 4; ++k) {
            float cge = change_term(f, k, n) * inv;
            out[k] = pow5(1.0f - cge) * f[k];
        }
        long long j0 = n - 4;
        #pragma unroll
        for (int k = 0; k < 4; ++k) {
            long long j = j0 + k;
            float cge = change_term(f, j, n) * inv;
            out[j] = pow5(1.0f - cge) * f[j];
        }
    }
}

extern "C" void kernel_launch(void* const* d_in, const int* in_sizes, int n_in,
                              void* d_out, int out_size, void* d_ws, size_t ws_size,
                              hipStream_t stream) {
    const float* f = (const float*)d_in[0];
    float* out = (float*)d_out;
    float* partials = (float*)d_ws;
    long long n = (long long)in_sizes[0];
    int nvec = (int)(n / 4);  // n = 2^24, divisible by 4

    // clamp reduce grid so partials[] (rgrid floats) always fits in ws_size
    int rgrid = RGRID_MAX;
    if (ws_size > 0 && (size_t)rgrid * sizeof(float) > ws_size) {
        rgrid = (int)(ws_size / sizeof(float));
        if (rgrid > RGRID_MAX) rgrid = RGRID_MAX;
        if (rgrid < 1) rgrid = 1;
    }

    reduce_change_kernel<<<rgrid, BLOCK, 0, stream>>>(f, nvec, n, partials);

    int M = nvec - 2;
    int T = (M + 3) >> 2;
    int fgrid = (T + BLOCK - 1) / BLOCK;
    finalize_kernel<<<fgrid, BLOCK, 0, stream>>>(f, nvec, n, partials, rgrid, out);
}